// Round 12
// baseline (51.482 us; speedup 1.0000x reference)
//
#include <hip/hip_runtime.h>

#define HDIM 1024
#define NW 18                 // 6 gate rows + 12 expert rows (e*2+l)
#define NTHREADS 512          // 8 waves, ONE LDS copy, 2 waves/SIMD
#define RPT 4                 // rows per lane
#define ROWS_PER_BLOCK 256    // 8 waves x 8 clusters x 4 rows
#define NJ 32                 // j-steps of 32 floats (128B) per row

typedef float f32x4 __attribute__((ext_vector_type(4)));

// R12 = R11's pattern at 2 waves/SIMD via one 512-thread block per CU.
//  - R11 (1 wave/SIMD) leaves waves idle ~70% of wall; R10 proved the memory
//    system delivers far more when requests overlap. 8 waves share one 72KB
//    LDS weight copy; when a wave stalls on vmcnt, its SIMD-partner computes.
//  - VGPR discipline (R5 lesson): RPT=4 (acc 72 + buf 32), bias loads in the
//    EPILOGUE only, rows recomputed at store -> ~125 live under the (512,2)
//    cap of 128. Check: WRITE_SIZE must stay ~0.5MB (no spill).
//  - Keeps R7/R11 wins: plain (non-nt) loads, inter-wave phase rotation,
//    8-lane clusters / 128B chunks, LDS [slot][w] broadcast reads,
//    distance-1 static double buffer.
__global__ __launch_bounds__(NTHREADS, 2)
void hardmoe_kernel(const float* __restrict__ cls,
                    const float* __restrict__ gate_w,
                    const float* __restrict__ gate_b,
                    const float* __restrict__ expert_w,
                    const float* __restrict__ expert_b,
                    float* __restrict__ out, int B)
{
    __shared__ f32x4 Wl[256 * NW];   // 72 KB, one copy for all 8 waves

    const int t = threadIdx.x;

    // ---- Stage weights: 512 threads x 9 f32x4 each (coalesced within each w) ----
    for (int i = t; i < NW * 256; i += NTHREADS) {
        int w = i >> 8;          // 0..17
        int s = i & 255;         // f32x4 slot
        const float* src = (w < 6) ? (gate_w + (size_t)w * HDIM)
                                   : (expert_w + (size_t)(w - 6) * HDIM);
        Wl[s * NW + w] = *(reinterpret_cast<const f32x4*>(src) + s);
    }
    __syncthreads();

    const int wv = t >> 6;       // wave 0..7
    const int l  = t & 63;
    const int s8 = l >> 3;       // cluster 0..7
    const int c  = l & 7;        // col sublane 0..7

    // Phase rotation: blk*9 covers all residues (gcd(9,32)=1); wv*4 spreads
    // the 8 waves across all 32 windows.
    const int phase = (blockIdx.x * 9 + (wv << 2)) & (NJ - 1);

    const int wavebase = blockIdx.x * ROWS_PER_BLOCK + wv * (8 * RPT);

    const float* px[RPT];
#pragma unroll
    for (int k = 0; k < RPT; ++k) {
        int r = wavebase + k * 8 + s8;
        int rc = r < B ? r : B - 1;
        px[k] = cls + (size_t)rc * HDIM + c * 4;
    }

    float acc[RPT][NW];
#pragma unroll
    for (int k = 0; k < RPT; ++k)
#pragma unroll
        for (int w = 0; w < NW; ++w) acc[k][w] = 0.f;

    f32x4 xA[RPT], xB[RPT];
#pragma unroll
    for (int k = 0; k < RPT; ++k)
        xA[k] = *reinterpret_cast<const f32x4*>(px[k] + (size_t)phase * 32);

    for (int jj = 0; jj < NJ; jj += 2) {
        const int ja = (jj + phase) & (NJ - 1);
        const int jb = (jj + 1 + phase) & (NJ - 1);
        const int jc = (jj + 2 + phase) & (NJ - 1);

        // prefetch column jb
#pragma unroll
        for (int k = 0; k < RPT; ++k)
            xB[k] = *reinterpret_cast<const f32x4*>(px[k] + (size_t)jb * 32);
        // compute column ja with xA
        {
            const f32x4* wp = &Wl[(ja * 8 + c) * NW];
#pragma unroll
            for (int w = 0; w < NW; ++w) {
                f32x4 wf = wp[w];
#pragma unroll
                for (int k = 0; k < RPT; ++k) {
                    float a = acc[k][w];
                    a = fmaf(xA[k].x, wf.x, a);
                    a = fmaf(xA[k].y, wf.y, a);
                    a = fmaf(xA[k].z, wf.z, a);
                    a = fmaf(xA[k].w, wf.w, a);
                    acc[k][w] = a;
                }
            }
        }
        // prefetch column jc
        if (jj + 2 < NJ) {
#pragma unroll
            for (int k = 0; k < RPT; ++k)
                xA[k] = *reinterpret_cast<const f32x4*>(px[k] + (size_t)jc * 32);
        }
        // compute column jb with xB
        {
            const f32x4* wq = &Wl[(jb * 8 + c) * NW];
#pragma unroll
            for (int w = 0; w < NW; ++w) {
                f32x4 wf = wq[w];
#pragma unroll
                for (int k = 0; k < RPT; ++k) {
                    float a = acc[k][w];
                    a = fmaf(xB[k].x, wf.x, a);
                    a = fmaf(xB[k].y, wf.y, a);
                    a = fmaf(xB[k].z, wf.z, a);
                    a = fmaf(xB[k].w, wf.w, a);
                    acc[k][w] = a;
                }
            }
        }
    }

    // ---- Reduce across the 8-lane cluster: xor 1,2,4 ----
#pragma unroll
    for (int k = 0; k < RPT; ++k)
#pragma unroll
        for (int w = 0; w < NW; ++w) {
            float v = acc[k][w];
            v += __shfl_xor(v, 1);
            v += __shfl_xor(v, 2);
            v += __shfl_xor(v, 4);
            acc[k][w] = v;
        }

    // ---- Biases loaded ONLY now (keeps main-loop live set under 128 VGPR) ----
    float gb[6], eb[12];
#pragma unroll
    for (int e = 0; e < 6; ++e) gb[e] = gate_b[e];
#pragma unroll
    for (int k = 0; k < 12; ++k) eb[k] = expert_b[k];

    // ---- Per row: gate argmax (strict >, first-max tiebreak) + expert select ----
#pragma unroll
    for (int k = 0; k < RPT; ++k) {
        float best = acc[k][0] + gb[0];
        int idx = 0;
#pragma unroll
        for (int e = 1; e < 6; ++e) {
            float v = acc[k][e] + gb[e];
            if (v > best) { best = v; idx = e; }
        }
        float o0 = 0.f, o1 = 0.f;
#pragma unroll
        for (int e = 0; e < 6; ++e) {
            bool m = (idx == e);
            o0 = m ? (acc[k][6 + 2 * e] + eb[2 * e])     : o0;
            o1 = m ? (acc[k][7 + 2 * e] + eb[2 * e + 1]) : o1;
        }
        const int row = wavebase + k * 8 + s8;
        if (c == 0 && row < B)
            *reinterpret_cast<float2*>(out + (size_t)row * 2) = make_float2(o0, o1);
    }
}

extern "C" void kernel_launch(void* const* d_in, const int* in_sizes, int n_in,
                              void* d_out, int out_size, void* d_ws, size_t ws_size,
                              hipStream_t stream) {
    const float* cls      = (const float*)d_in[0];
    const float* gate_w   = (const float*)d_in[1];
    const float* gate_b   = (const float*)d_in[2];
    const float* expert_w = (const float*)d_in[3];
    const float* expert_b = (const float*)d_in[4];
    float* out = (float*)d_out;

    const int B = in_sizes[0] / HDIM;
    const int grid = (B + ROWS_PER_BLOCK - 1) / ROWS_PER_BLOCK;

    hardmoe_kernel<<<grid, NTHREADS, 0, stream>>>(cls, gate_w, gate_b,
                                                  expert_w, expert_b, out, B);
}